// Round 1
// baseline (765.372 us; speedup 1.0000x reference)
//
#include <hip/hip_runtime.h>

#define NH 4
#define ND 16
#define HD 64
#define IN_DIM 128
#define NEG_SLOPE 0.2f

// ---------------- K1: feat = x @ fc_W, plus el/er per node ----------------
__global__ __launch_bounds__(256) void k1_feat(
    const float* __restrict__ x, const float* __restrict__ fcW,
    const float* __restrict__ attn_l, const float* __restrict__ attn_r,
    float* __restrict__ feat, float* __restrict__ el, float* __restrict__ er, int n)
{
  __shared__ float sW[IN_DIM * HD];   // 32 KB
  __shared__ float sx[8][IN_DIM];     // 4 KB
  for (int i = threadIdx.x; i < IN_DIM * HD; i += 256) sW[i] = fcW[i];
  const int grp = threadIdx.x >> 6;   // 0..3
  const int j   = threadIdx.x & 63;   // output column (h*16+d)
  const float al = attn_l[j], ar = attn_r[j];

  for (int base = blockIdx.x * 8; base < n; base += gridDim.x * 8) {
    __syncthreads();
    for (int i = threadIdx.x; i < 8 * IN_DIM; i += 256) {
      int r = i >> 7, c = i & 127;
      int row = base + r;
      sx[r][c] = (row < n) ? x[(size_t)row * IN_DIM + c] : 0.f;
    }
    __syncthreads();
    float acc0 = 0.f, acc1 = 0.f;
#pragma unroll
    for (int k = 0; k < IN_DIM; ++k) {
      float w = sW[k * HD + j];
      acc0 = fmaf(sx[grp][k], w, acc0);
      acc1 = fmaf(sx[grp + 4][k], w, acc1);
    }
    float pl0 = acc0 * al, pr0 = acc0 * ar;
    float pl1 = acc1 * al, pr1 = acc1 * ar;
#pragma unroll
    for (int off = 8; off >= 1; off >>= 1) {
      pl0 += __shfl_xor(pl0, off);
      pr0 += __shfl_xor(pr0, off);
      pl1 += __shfl_xor(pl1, off);
      pr1 += __shfl_xor(pr1, off);
    }
    int row0 = base + grp, row1 = base + grp + 4;
    if (row0 < n) {
      feat[(size_t)row0 * HD + j] = acc0;
      if ((j & 15) == 0) { int h = j >> 4; el[row0 * NH + h] = pl0; er[row0 * NH + h] = pr0; }
    }
    if (row1 < n) {
      feat[(size_t)row1 * HD + j] = acc1;
      if ((j & 15) == 0) { int h = j >> 4; el[row1 * NH + h] = pl1; er[row1 * NH + h] = pr1; }
    }
  }
}

// ---------------- K2: ee[t][h] (tiny, single block) ----------------
__global__ __launch_bounds__(128) void k2_ee(
    const float* __restrict__ edge_emb, const float* __restrict__ fc_e_W,
    const float* __restrict__ attn_e, float* __restrict__ ee)
{
  __shared__ float sef[8][128];
  int t = threadIdx.x;
  for (int r = 0; r < 8; ++r) {
    float acc = 0.f;
#pragma unroll
    for (int k = 0; k < 32; ++k) acc = fmaf(edge_emb[r * 32 + k], fc_e_W[k * 128 + t], acc);
    sef[r][t] = acc;
  }
  __syncthreads();
  if (t < 32) {
    int r = t >> 2, h = t & 3;
    float acc = 0.f;
#pragma unroll
    for (int e2 = 0; e2 < 32; ++e2) acc += sef[r][h * 32 + e2] * attn_e[h * 32 + e2];
    ee[r * NH + h] = acc;
  }
}

// ---------------- K3: denom[d][h] += exp(leaky(s)) ----------------
__global__ __launch_bounds__(256) void k3_denom(
    const int* __restrict__ src, const int* __restrict__ dst, const int* __restrict__ et,
    const float* __restrict__ el, const float* __restrict__ er, const float* __restrict__ ee,
    float* __restrict__ denom, int ne)
{
  int e = blockIdx.x * 256 + threadIdx.x;
  if (e >= ne) return;
  int s = src[e], d = dst[e], t = et[e];
#pragma unroll
  for (int h = 0; h < NH; ++h) {
    float sv = el[s * NH + h] + er[d * NH + h] + ee[t * NH + h];
    sv = sv > 0.f ? sv : NEG_SLOPE * sv;
    atomicAdd(&denom[d * NH + h], __expf(sv));
  }
}

// ---------------- K4: out[d] += (p/denom[d]) * feat[s], wave per edge ----------------
__global__ __launch_bounds__(256) void k4_agg(
    const int* __restrict__ src, const int* __restrict__ dst, const int* __restrict__ et,
    const float* __restrict__ el, const float* __restrict__ er, const float* __restrict__ ee,
    const float* __restrict__ denom, const float* __restrict__ feat,
    float* __restrict__ out, int ne)
{
  int gw = (blockIdx.x * 256 + threadIdx.x) >> 6;  // global wave id
  int lane = threadIdx.x & 63;
  int h = lane >> 4;
  int e_end = gw * 4 + 4; if (e_end > ne) e_end = ne;
  for (int e = gw * 4; e < e_end; ++e) {
    int s = src[e], d = dst[e], t = et[e];
    float sv = el[s * NH + h] + er[d * NH + h] + ee[t * NH + h];
    sv = sv > 0.f ? sv : NEG_SLOPE * sv;
    float a = __expf(sv) / denom[d * NH + h];
    float f = feat[(size_t)s * HD + lane];
    atomicAdd(&out[(size_t)d * HD + lane], a * f);
  }
}

extern "C" void kernel_launch(void* const* d_in, const int* in_sizes, int n_in,
                              void* d_out, int out_size, void* d_ws, size_t ws_size,
                              hipStream_t stream)
{
  const float* x        = (const float*)d_in[0];
  const int*   src      = (const int*)d_in[1];
  const int*   dst      = (const int*)d_in[2];
  const int*   etype    = (const int*)d_in[3];
  const float* fcW      = (const float*)d_in[4];
  const float* fceW     = (const float*)d_in[5];
  const float* edge_emb = (const float*)d_in[6];
  const float* attn_l   = (const float*)d_in[7];
  const float* attn_r   = (const float*)d_in[8];
  const float* attn_e   = (const float*)d_in[9];
  float* out = (float*)d_out;

  const int n  = in_sizes[0] / IN_DIM;   // 100000
  const int ne = in_sizes[1];            // 1600000

  char* ws = (char*)d_ws;
  float* feat  = (float*)ws;                                  // n*64 floats
  float* el    = (float*)(ws + (size_t)n * HD * sizeof(float));
  float* er    = el + (size_t)n * NH;
  float* denom = er + (size_t)n * NH;
  float* ee    = denom + (size_t)n * NH;                      // 32 floats

  hipMemsetAsync(denom, 0, (size_t)n * NH * sizeof(float), stream);
  hipMemsetAsync(out, 0, (size_t)out_size * sizeof(float), stream);

  k1_feat<<<(n + 7) / 8, 256, 0, stream>>>(x, fcW, attn_l, attn_r, feat, el, er, n);
  k2_ee<<<1, 128, 0, stream>>>(edge_emb, fceW, attn_e, ee);
  k3_denom<<<(ne + 255) / 256, 256, 0, stream>>>(src, dst, etype, el, er, ee, denom, ne);
  int nwaves = (ne + 3) / 4;
  k4_agg<<<(nwaves + 3) / 4, 256, 0, stream>>>(src, dst, etype, el, er, ee, denom, feat, out, ne);
}

// Round 2
// 670.923 us; speedup vs baseline: 1.1408x; 1.1408x over previous
//
#include <hip/hip_runtime.h>

#define NH 4
#define ND 16
#define HD 64
#define IN_DIM 128
#define NEG_SLOPE 0.2f

// ---------------- K1: feat = x @ fc_W, plus el/er per node ----------------
__global__ __launch_bounds__(256) void k1_feat(
    const float* __restrict__ x, const float* __restrict__ fcW,
    const float* __restrict__ attn_l, const float* __restrict__ attn_r,
    float* __restrict__ feat, float* __restrict__ el, float* __restrict__ er, int n)
{
  __shared__ float sW[IN_DIM * HD];   // 32 KB
  __shared__ float sx[16][IN_DIM];    // 8 KB
  for (int i = threadIdx.x; i < IN_DIM * HD; i += 256) sW[i] = fcW[i];
  const int grp = threadIdx.x >> 6;   // 0..3
  const int j   = threadIdx.x & 63;   // output column (h*16+d)
  const float al = attn_l[j], ar = attn_r[j];

  for (int base = blockIdx.x * 16; base < n; base += gridDim.x * 16) {
    __syncthreads();
    for (int i = threadIdx.x; i < 16 * IN_DIM; i += 256) {
      int r = i >> 7, c = i & 127;
      int row = base + r;
      sx[r][c] = (row < n) ? x[(size_t)row * IN_DIM + c] : 0.f;
    }
    __syncthreads();
    float a0 = 0.f, a1 = 0.f, a2 = 0.f, a3 = 0.f;
#pragma unroll 8
    for (int k = 0; k < IN_DIM; ++k) {
      float w = sW[k * HD + j];
      a0 = fmaf(sx[grp][k],      w, a0);
      a1 = fmaf(sx[grp + 4][k],  w, a1);
      a2 = fmaf(sx[grp + 8][k],  w, a2);
      a3 = fmaf(sx[grp + 12][k], w, a3);
    }
    float l0 = a0 * al, r0 = a0 * ar, l1 = a1 * al, r1 = a1 * ar;
    float l2 = a2 * al, r2 = a2 * ar, l3 = a3 * al, r3 = a3 * ar;
#pragma unroll
    for (int off = 8; off >= 1; off >>= 1) {
      l0 += __shfl_xor(l0, off); r0 += __shfl_xor(r0, off);
      l1 += __shfl_xor(l1, off); r1 += __shfl_xor(r1, off);
      l2 += __shfl_xor(l2, off); r2 += __shfl_xor(r2, off);
      l3 += __shfl_xor(l3, off); r3 += __shfl_xor(r3, off);
    }
    int h = j >> 4;
    int row;
    row = base + grp;
    if (row < n) { feat[(size_t)row * HD + j] = a0;
      if ((j & 15) == 0) { el[row * NH + h] = l0; er[row * NH + h] = r0; } }
    row = base + grp + 4;
    if (row < n) { feat[(size_t)row * HD + j] = a1;
      if ((j & 15) == 0) { el[row * NH + h] = l1; er[row * NH + h] = r1; } }
    row = base + grp + 8;
    if (row < n) { feat[(size_t)row * HD + j] = a2;
      if ((j & 15) == 0) { el[row * NH + h] = l2; er[row * NH + h] = r2; } }
    row = base + grp + 12;
    if (row < n) { feat[(size_t)row * HD + j] = a3;
      if ((j & 15) == 0) { el[row * NH + h] = l3; er[row * NH + h] = r3; } }
  }
}

// ---------------- K2: ee[t][h] (tiny, single block) ----------------
__global__ __launch_bounds__(128) void k2_ee(
    const float* __restrict__ edge_emb, const float* __restrict__ fc_e_W,
    const float* __restrict__ attn_e, float* __restrict__ ee)
{
  __shared__ float sef[8][128];
  int t = threadIdx.x;
  for (int r = 0; r < 8; ++r) {
    float acc = 0.f;
#pragma unroll
    for (int k = 0; k < 32; ++k) acc = fmaf(edge_emb[r * 32 + k], fc_e_W[k * 128 + t], acc);
    sef[r][t] = acc;
  }
  __syncthreads();
  if (t < 32) {
    int r = t >> 2, h = t & 3;
    float acc = 0.f;
#pragma unroll
    for (int e2 = 0; e2 < 32; ++e2) acc += sef[r][h * 32 + e2] * attn_e[h * 32 + e2];
    ee[r * NH + h] = acc;
  }
}

// ---------------- K3a: histogram of dst ----------------
__global__ __launch_bounds__(256) void k_hist(
    const int* __restrict__ dst, int* __restrict__ cnt, int ne)
{
  int e = blockIdx.x * 256 + threadIdx.x;
  if (e < ne) atomicAdd(&cnt[dst[e]], 1);
}

// ---------------- K3b: exclusive scan (single block) ----------------
// in: next[] holds counts; out: rowptr[0..n] = offsets, next[] = start offsets
__global__ __launch_bounds__(1024) void k_scan(
    int* __restrict__ next, int* __restrict__ rowptr, int n)
{
  __shared__ int wsum[16];
  __shared__ int wbase[16];
  int t = threadIdx.x;
  int chunk = (n + 1023) >> 10;
  int lo = t * chunk; if (lo > n) lo = n;
  int hi = lo + chunk; if (hi > n) hi = n;
  int s = 0;
  for (int i = lo; i < hi; ++i) s += next[i];
  int lane = t & 63, w = t >> 6;
  int inc = s;
#pragma unroll
  for (int off = 1; off < 64; off <<= 1) {
    int v = __shfl_up(inc, off);
    if (lane >= off) inc += v;
  }
  if (lane == 63) wsum[w] = inc;
  __syncthreads();
  if (t == 0) { int r = 0; for (int i = 0; i < 16; ++i) { wbase[i] = r; r += wsum[i]; } }
  __syncthreads();
  int run = wbase[w] + inc - s;   // exclusive prefix for this thread's chunk
  for (int i = lo; i < hi; ++i) {
    int c = next[i];
    rowptr[i] = run;
    next[i] = run;
    run += c;
  }
  if (hi == n) rowptr[n] = run;
}

// ---------------- K3c: scatter packed (src | etype<<17) records ----------------
__global__ __launch_bounds__(256) void k_scatter(
    const int* __restrict__ src, const int* __restrict__ dst, const int* __restrict__ et,
    int* __restrict__ next, unsigned* __restrict__ recs, int ne)
{
  int e = blockIdx.x * 256 + threadIdx.x;
  if (e >= ne) return;
  int d = dst[e];
  int pos = atomicAdd(&next[d], 1);
  recs[pos] = (unsigned)src[e] | ((unsigned)et[e] << 17);
}

// ---------------- K4: wave per dst — softmax + aggregate, single write ----------------
__global__ __launch_bounds__(256) void k_agg(
    const int* __restrict__ rowptr, const unsigned* __restrict__ recs,
    const float* __restrict__ el, const float* __restrict__ er, const float* __restrict__ ee,
    const float* __restrict__ feat, float* __restrict__ out, int n)
{
  int d = (blockIdx.x * 256 + threadIdx.x) >> 6;
  if (d >= n) return;
  int lane = threadIdx.x & 63;
  int h = lane >> 4;
  int beg = rowptr[d], end = rowptr[d + 1];
  float erd = er[d * NH + h];
  float acc = 0.f, den = 0.f;
  for (int i = beg; i < end; ++i) {
    unsigned r = recs[i];
    int s = r & 0x1FFFF;
    int t = r >> 17;
    float sv = el[s * NH + h] + erd + ee[t * NH + h];
    sv = sv > 0.f ? sv : NEG_SLOPE * sv;
    float p = __expf(sv);
    den += p;
    acc = fmaf(p, feat[(size_t)s * HD + lane], acc);
  }
  out[(size_t)d * HD + lane] = den > 0.f ? acc / den : 0.f;
}

extern "C" void kernel_launch(void* const* d_in, const int* in_sizes, int n_in,
                              void* d_out, int out_size, void* d_ws, size_t ws_size,
                              hipStream_t stream)
{
  const float* x        = (const float*)d_in[0];
  const int*   src      = (const int*)d_in[1];
  const int*   dst      = (const int*)d_in[2];
  const int*   etype    = (const int*)d_in[3];
  const float* fcW      = (const float*)d_in[4];
  const float* fceW     = (const float*)d_in[5];
  const float* edge_emb = (const float*)d_in[6];
  const float* attn_l   = (const float*)d_in[7];
  const float* attn_r   = (const float*)d_in[8];
  const float* attn_e   = (const float*)d_in[9];
  float* out = (float*)d_out;

  const int n  = in_sizes[0] / IN_DIM;   // 100000
  const int ne = in_sizes[1];            // 1600000

  char* ws = (char*)d_ws;
  size_t off = 0;
  float* feat  = (float*)(ws + off); off += (size_t)n * HD * sizeof(float);
  float* el    = (float*)(ws + off); off += (size_t)n * NH * sizeof(float);
  float* er    = (float*)(ws + off); off += (size_t)n * NH * sizeof(float);
  float* ee    = (float*)(ws + off); off += 256;
  int* rowptr  = (int*)(ws + off);   off += ((size_t)n + 1) * sizeof(int);
  int* next    = (int*)(ws + off);   off += (size_t)n * sizeof(int);
  unsigned* recs = (unsigned*)(ws + off); off += (size_t)ne * sizeof(unsigned);

  hipMemsetAsync(next, 0, (size_t)n * sizeof(int), stream);

  k1_feat<<<1024, 256, 0, stream>>>(x, fcW, attn_l, attn_r, feat, el, er, n);
  k2_ee<<<1, 128, 0, stream>>>(edge_emb, fceW, attn_e, ee);
  k_hist<<<(ne + 255) / 256, 256, 0, stream>>>(dst, next, ne);
  k_scan<<<1, 1024, 0, stream>>>(next, rowptr, n);
  k_scatter<<<(ne + 255) / 256, 256, 0, stream>>>(src, dst, etype, next, recs, ne);
  int nwaves = n;  // one wave per dst
  k_agg<<<(nwaves * 64 + 255) / 256, 256, 0, stream>>>(rowptr, recs, el, er, ee, feat, out, n);
}

// Round 3
// 452.724 us; speedup vs baseline: 1.6906x; 1.4820x over previous
//
#include <hip/hip_runtime.h>

#define NH 4
#define ND 16
#define HD 64
#define IN_DIM 128
#define NEG_SLOPE 0.2f

// ---------------- K1: feat = x @ fc_W, plus el/er per node ----------------
__global__ __launch_bounds__(256) void k1_feat(
    const float* __restrict__ x, const float* __restrict__ fcW,
    const float* __restrict__ attn_l, const float* __restrict__ attn_r,
    float* __restrict__ feat, float* __restrict__ el, float* __restrict__ er, int n)
{
  __shared__ float sW[IN_DIM * HD];   // 32 KB
  __shared__ float sx[16][IN_DIM];    // 8 KB
  for (int i = threadIdx.x; i < IN_DIM * HD; i += 256) sW[i] = fcW[i];
  const int grp = threadIdx.x >> 6;   // 0..3
  const int j   = threadIdx.x & 63;   // output column (h*16+d)
  const float al = attn_l[j], ar = attn_r[j];

  for (int base = blockIdx.x * 16; base < n; base += gridDim.x * 16) {
    __syncthreads();
    for (int i = threadIdx.x; i < 16 * IN_DIM; i += 256) {
      int r = i >> 7, c = i & 127;
      int row = base + r;
      sx[r][c] = (row < n) ? x[(size_t)row * IN_DIM + c] : 0.f;
    }
    __syncthreads();
    float a0 = 0.f, a1 = 0.f, a2 = 0.f, a3 = 0.f;
#pragma unroll 8
    for (int k = 0; k < IN_DIM; ++k) {
      float w = sW[k * HD + j];
      a0 = fmaf(sx[grp][k],      w, a0);
      a1 = fmaf(sx[grp + 4][k],  w, a1);
      a2 = fmaf(sx[grp + 8][k],  w, a2);
      a3 = fmaf(sx[grp + 12][k], w, a3);
    }
    float l0 = a0 * al, r0 = a0 * ar, l1 = a1 * al, r1 = a1 * ar;
    float l2 = a2 * al, r2 = a2 * ar, l3 = a3 * al, r3 = a3 * ar;
#pragma unroll
    for (int off = 8; off >= 1; off >>= 1) {
      l0 += __shfl_xor(l0, off); r0 += __shfl_xor(r0, off);
      l1 += __shfl_xor(l1, off); r1 += __shfl_xor(r1, off);
      l2 += __shfl_xor(l2, off); r2 += __shfl_xor(r2, off);
      l3 += __shfl_xor(l3, off); r3 += __shfl_xor(r3, off);
    }
    int h = j >> 4;
    int row;
    row = base + grp;
    if (row < n) { feat[(size_t)row * HD + j] = a0;
      if ((j & 15) == 0) { el[row * NH + h] = l0; er[row * NH + h] = r0; } }
    row = base + grp + 4;
    if (row < n) { feat[(size_t)row * HD + j] = a1;
      if ((j & 15) == 0) { el[row * NH + h] = l1; er[row * NH + h] = r1; } }
    row = base + grp + 8;
    if (row < n) { feat[(size_t)row * HD + j] = a2;
      if ((j & 15) == 0) { el[row * NH + h] = l2; er[row * NH + h] = r2; } }
    row = base + grp + 12;
    if (row < n) { feat[(size_t)row * HD + j] = a3;
      if ((j & 15) == 0) { el[row * NH + h] = l3; er[row * NH + h] = r3; } }
  }
}

// ---------------- K2: ee[t][h] (tiny, single block) ----------------
__global__ __launch_bounds__(128) void k2_ee(
    const float* __restrict__ edge_emb, const float* __restrict__ fc_e_W,
    const float* __restrict__ attn_e, float* __restrict__ ee)
{
  __shared__ float sef[8][128];
  int t = threadIdx.x;
  for (int r = 0; r < 8; ++r) {
    float acc = 0.f;
#pragma unroll
    for (int k = 0; k < 32; ++k) acc = fmaf(edge_emb[r * 32 + k], fc_e_W[k * 128 + t], acc);
    sef[r][t] = acc;
  }
  __syncthreads();
  if (t < 32) {
    int r = t >> 2, h = t & 3;
    float acc = 0.f;
#pragma unroll
    for (int e2 = 0; e2 < 32; ++e2) acc += sef[r][h * 32 + e2] * attn_e[h * 32 + e2];
    ee[r * NH + h] = acc;
  }
}

// ---------------- K3a: histogram of dst (into rowptr, pre-zeroed) ----------------
__global__ __launch_bounds__(256) void k_hist(
    const int* __restrict__ dst, int* __restrict__ cnt, int ne)
{
  int e = blockIdx.x * 256 + threadIdx.x;
  if (e < ne) atomicAdd(&cnt[dst[e]], 1);
}

// ---------------- K3b-1: per-block partial sums (512 items / block) ----------------
__global__ __launch_bounds__(512) void k_psum(
    const int* __restrict__ cnt, int* __restrict__ blocksum, int n)
{
  __shared__ int ws[8];
  int i = blockIdx.x * 512 + threadIdx.x;
  int c = (i < n) ? cnt[i] : 0;
#pragma unroll
  for (int off = 32; off >= 1; off >>= 1) c += __shfl_xor(c, off);
  int lane = threadIdx.x & 63, w = threadIdx.x >> 6;
  if (lane == 0) ws[w] = c;
  __syncthreads();
  if (threadIdx.x == 0) {
    int r = 0;
#pragma unroll
    for (int k = 0; k < 8; ++k) r += ws[k];
    blocksum[blockIdx.x] = r;
  }
}

// ---------------- K3b-2: scan the block sums (nb <= 256), set rowptr[n] ----------------
__global__ __launch_bounds__(256) void k_scan_blk(
    const int* __restrict__ blocksum, int* __restrict__ blockbase,
    int nb, int* __restrict__ rowptr, int n, int ne)
{
  __shared__ int ws[4], wb[4];
  int t = threadIdx.x;
  int c = (t < nb) ? blocksum[t] : 0;
  int lane = t & 63, w = t >> 6;
  int inc = c;
#pragma unroll
  for (int off = 1; off < 64; off <<= 1) {
    int v = __shfl_up(inc, off);
    if (lane >= off) inc += v;
  }
  if (lane == 63) ws[w] = inc;
  __syncthreads();
  if (t == 0) { int r = 0; for (int k = 0; k < 4; ++k) { wb[k] = r; r += ws[k]; } }
  __syncthreads();
  if (t < nb) blockbase[t] = wb[w] + inc - c;
  if (t == 0) rowptr[n] = ne;
}

// ---------------- K3b-3: block-local scan + base; rowptr (in)=hist, (out)=offsets ----------------
__global__ __launch_bounds__(512) void k_scan_apply(
    int* __restrict__ rowptr, const int* __restrict__ blockbase,
    int* __restrict__ next, int n)
{
  __shared__ int ws[8], wb[8];
  int i = blockIdx.x * 512 + threadIdx.x;
  int c = (i < n) ? rowptr[i] : 0;
  int lane = threadIdx.x & 63, w = threadIdx.x >> 6;
  int inc = c;
#pragma unroll
  for (int off = 1; off < 64; off <<= 1) {
    int v = __shfl_up(inc, off);
    if (lane >= off) inc += v;
  }
  if (lane == 63) ws[w] = inc;
  __syncthreads();
  if (threadIdx.x == 0) { int r = 0; for (int k = 0; k < 8; ++k) { wb[k] = r; r += ws[k]; } }
  __syncthreads();
  int ex = blockbase[blockIdx.x] + wb[w] + inc - c;   // exclusive prefix
  if (i < n) { rowptr[i] = ex; next[i] = ex; }
}

// ---------------- K3c: scatter packed (src | etype<<17) records ----------------
__global__ __launch_bounds__(256) void k_scatter(
    const int* __restrict__ src, const int* __restrict__ dst, const int* __restrict__ et,
    int* __restrict__ next, unsigned* __restrict__ recs, int ne)
{
  int e = blockIdx.x * 256 + threadIdx.x;
  if (e >= ne) return;
  int d = dst[e];
  int pos = atomicAdd(&next[d], 1);
  recs[pos] = (unsigned)src[e] | ((unsigned)et[e] << 17);
}

// ---------------- K4: wave per dst — softmax + aggregate, single write ----------------
__global__ __launch_bounds__(256) void k_agg(
    const int* __restrict__ rowptr, const unsigned* __restrict__ recs,
    const float* __restrict__ el, const float* __restrict__ er, const float* __restrict__ ee,
    const float* __restrict__ feat, float* __restrict__ out, int n)
{
  int d = (blockIdx.x * 256 + threadIdx.x) >> 6;
  if (d >= n) return;
  int lane = threadIdx.x & 63;
  int h = lane >> 4;
  int beg = rowptr[d], end = rowptr[d + 1];
  float erd = er[d * NH + h];
  float acc = 0.f, den = 0.f;
  for (int i = beg; i < end; ++i) {
    unsigned r = recs[i];
    int s = r & 0x1FFFF;
    int t = r >> 17;
    float sv = el[s * NH + h] + erd + ee[t * NH + h];
    sv = sv > 0.f ? sv : NEG_SLOPE * sv;
    float p = __expf(sv);
    den += p;
    acc = fmaf(p, feat[(size_t)s * HD + lane], acc);
  }
  out[(size_t)d * HD + lane] = den > 0.f ? acc / den : 0.f;
}

extern "C" void kernel_launch(void* const* d_in, const int* in_sizes, int n_in,
                              void* d_out, int out_size, void* d_ws, size_t ws_size,
                              hipStream_t stream)
{
  const float* x        = (const float*)d_in[0];
  const int*   src      = (const int*)d_in[1];
  const int*   dst      = (const int*)d_in[2];
  const int*   etype    = (const int*)d_in[3];
  const float* fcW      = (const float*)d_in[4];
  const float* fceW     = (const float*)d_in[5];
  const float* edge_emb = (const float*)d_in[6];
  const float* attn_l   = (const float*)d_in[7];
  const float* attn_r   = (const float*)d_in[8];
  const float* attn_e   = (const float*)d_in[9];
  float* out = (float*)d_out;

  const int n  = in_sizes[0] / IN_DIM;   // 100000
  const int ne = in_sizes[1];            // 1600000
  const int nb = (n + 511) / 512;        // 196 scan blocks

  char* ws = (char*)d_ws;
  size_t off = 0;
  float* feat  = (float*)(ws + off); off += (size_t)n * HD * sizeof(float);
  float* el    = (float*)(ws + off); off += (size_t)n * NH * sizeof(float);
  float* er    = (float*)(ws + off); off += (size_t)n * NH * sizeof(float);
  float* ee    = (float*)(ws + off); off += 256;
  int* rowptr  = (int*)(ws + off);   off += ((size_t)n + 1) * sizeof(int);
  int* next    = (int*)(ws + off);   off += (size_t)n * sizeof(int);
  int* blocksum= (int*)(ws + off);   off += (size_t)nb * sizeof(int);
  int* blockbase=(int*)(ws + off);   off += (size_t)nb * sizeof(int);
  unsigned* recs = (unsigned*)(ws + off); off += (size_t)ne * sizeof(unsigned);

  hipMemsetAsync(rowptr, 0, (size_t)n * sizeof(int), stream);

  k1_feat<<<1024, 256, 0, stream>>>(x, fcW, attn_l, attn_r, feat, el, er, n);
  k2_ee<<<1, 128, 0, stream>>>(edge_emb, fceW, attn_e, ee);
  k_hist<<<(ne + 255) / 256, 256, 0, stream>>>(dst, rowptr, ne);
  k_psum<<<nb, 512, 0, stream>>>(rowptr, blocksum, n);
  k_scan_blk<<<1, 256, 0, stream>>>(blocksum, blockbase, nb, rowptr, n, ne);
  k_scan_apply<<<nb, 512, 0, stream>>>(rowptr, blockbase, next, n);
  k_scatter<<<(ne + 255) / 256, 256, 0, stream>>>(src, dst, etype, next, recs, ne);
  k_agg<<<((size_t)n * 64 + 255) / 256, 256, 0, stream>>>(rowptr, recs, el, er, ee, feat, out, n);
}

// Round 4
// 350.224 us; speedup vs baseline: 2.1854x; 1.2927x over previous
//
#include <hip/hip_runtime.h>

#define NH 4
#define ND 16
#define HD 64
#define IN_DIM 128
#define NEG_SLOPE 0.2f

__device__ inline unsigned short f2bf(float f) {   // RNE fp32 -> bf16
  unsigned u = __float_as_uint(f);
  u += 0x7FFFu + ((u >> 16) & 1u);
  return (unsigned short)(u >> 16);
}

// ---- K1: feat(bf16) = x @ fc_W, el/er per node, fused dst-histogram tail ----
__global__ __launch_bounds__(256) void k1_feat(
    const float* __restrict__ x, const float* __restrict__ fcW,
    const float* __restrict__ attn_l, const float* __restrict__ attn_r,
    unsigned short* __restrict__ featb, float* __restrict__ el, float* __restrict__ er,
    const int* __restrict__ dst, int* __restrict__ cnt, int n, int ne)
{
  __shared__ float sW[IN_DIM * HD];   // 32 KB
  __shared__ float sx[16][IN_DIM];    // 8 KB
  for (int i = threadIdx.x; i < IN_DIM * HD; i += 256) sW[i] = fcW[i];
  const int grp = threadIdx.x >> 6;   // 0..3
  const int j   = threadIdx.x & 63;   // output column (h*16+d)
  const float al = attn_l[j], ar = attn_r[j];

  for (int base = blockIdx.x * 16; base < n; base += gridDim.x * 16) {
    __syncthreads();
    for (int i = threadIdx.x; i < 16 * IN_DIM; i += 256) {
      int r = i >> 7, c = i & 127;
      int row = base + r;
      sx[r][c] = (row < n) ? x[(size_t)row * IN_DIM + c] : 0.f;
    }
    __syncthreads();
    float a0 = 0.f, a1 = 0.f, a2 = 0.f, a3 = 0.f;
#pragma unroll 8
    for (int k = 0; k < IN_DIM; ++k) {
      float w = sW[k * HD + j];
      a0 = fmaf(sx[grp][k],      w, a0);
      a1 = fmaf(sx[grp + 4][k],  w, a1);
      a2 = fmaf(sx[grp + 8][k],  w, a2);
      a3 = fmaf(sx[grp + 12][k], w, a3);
    }
    float l0 = a0 * al, r0 = a0 * ar, l1 = a1 * al, r1 = a1 * ar;
    float l2 = a2 * al, r2 = a2 * ar, l3 = a3 * al, r3 = a3 * ar;
#pragma unroll
    for (int off = 8; off >= 1; off >>= 1) {
      l0 += __shfl_xor(l0, off); r0 += __shfl_xor(r0, off);
      l1 += __shfl_xor(l1, off); r1 += __shfl_xor(r1, off);
      l2 += __shfl_xor(l2, off); r2 += __shfl_xor(r2, off);
      l3 += __shfl_xor(l3, off); r3 += __shfl_xor(r3, off);
    }
    int h = j >> 4;
    int row;
    row = base + grp;
    if (row < n) { featb[(size_t)row * HD + j] = f2bf(a0);
      if ((j & 15) == 0) { el[row * NH + h] = l0; er[row * NH + h] = r0; } }
    row = base + grp + 4;
    if (row < n) { featb[(size_t)row * HD + j] = f2bf(a1);
      if ((j & 15) == 0) { el[row * NH + h] = l1; er[row * NH + h] = r1; } }
    row = base + grp + 8;
    if (row < n) { featb[(size_t)row * HD + j] = f2bf(a2);
      if ((j & 15) == 0) { el[row * NH + h] = l2; er[row * NH + h] = r2; } }
    row = base + grp + 12;
    if (row < n) { featb[(size_t)row * HD + j] = f2bf(a3);
      if ((j & 15) == 0) { el[row * NH + h] = l3; er[row * NH + h] = r3; } }
  }
  // fused dst histogram (cnt pre-zeroed by memset)
  for (int e = blockIdx.x * 256 + threadIdx.x; e < ne; e += gridDim.x * 256)
    atomicAdd(&cnt[dst[e]], 1);
}

// ---- K2a: per-block partial sums of counts (512 items / block) ----
__global__ __launch_bounds__(512) void k_psum(
    const int* __restrict__ cnt, int* __restrict__ blocksum, int n)
{
  __shared__ int ws[8];
  int i = blockIdx.x * 512 + threadIdx.x;
  int c = (i < n) ? cnt[i] : 0;
#pragma unroll
  for (int off = 32; off >= 1; off >>= 1) c += __shfl_xor(c, off);
  int lane = threadIdx.x & 63, w = threadIdx.x >> 6;
  if (lane == 0) ws[w] = c;
  __syncthreads();
  if (threadIdx.x == 0) {
    int r = 0;
#pragma unroll
    for (int k = 0; k < 8; ++k) r += ws[k];
    blocksum[blockIdx.x] = r;
  }
}

// ---- K2b: scan block sums (nb <= 256) + tiny ee[t][h] computation fused ----
__global__ __launch_bounds__(256) void k_scan_blk(
    const int* __restrict__ blocksum, int* __restrict__ blockbase,
    int nb, int* __restrict__ rowptr, int n, int ne,
    const float* __restrict__ edge_emb, const float* __restrict__ fc_e_W,
    const float* __restrict__ attn_e, float* __restrict__ ee)
{
  __shared__ int ws[4], wb[4];
  __shared__ float sef[8][128];
  int t = threadIdx.x;
  int c = (t < nb) ? blocksum[t] : 0;
  int lane = t & 63, w = t >> 6;
  int inc = c;
#pragma unroll
  for (int off = 1; off < 64; off <<= 1) {
    int v = __shfl_up(inc, off);
    if (lane >= off) inc += v;
  }
  if (lane == 63) ws[w] = inc;
  if (t < 128) {
    for (int r = 0; r < 8; ++r) {
      float acc = 0.f;
#pragma unroll
      for (int k = 0; k < 32; ++k) acc = fmaf(edge_emb[r * 32 + k], fc_e_W[k * 128 + t], acc);
      sef[r][t] = acc;
    }
  }
  __syncthreads();
  if (t == 0) { int r = 0; for (int k = 0; k < 4; ++k) { wb[k] = r; r += ws[k]; } }
  if (t < 32) {
    int r = t >> 2, h = t & 3;
    float acc = 0.f;
#pragma unroll
    for (int e2 = 0; e2 < 32; ++e2) acc += sef[r][h * 32 + e2] * attn_e[h * 32 + e2];
    ee[r * NH + h] = acc;
  }
  __syncthreads();
  if (t < nb) blockbase[t] = wb[w] + inc - c;
  if (t == 0) rowptr[n] = ne;
}

// ---- K2c: block-local scan + base; rowptr (in)=counts, (out)=offsets ----
__global__ __launch_bounds__(512) void k_scan_apply(
    int* __restrict__ rowptr, const int* __restrict__ blockbase,
    int* __restrict__ next, int n)
{
  __shared__ int ws[8], wb[8];
  int i = blockIdx.x * 512 + threadIdx.x;
  int c = (i < n) ? rowptr[i] : 0;
  int lane = threadIdx.x & 63, w = threadIdx.x >> 6;
  int inc = c;
#pragma unroll
  for (int off = 1; off < 64; off <<= 1) {
    int v = __shfl_up(inc, off);
    if (lane >= off) inc += v;
  }
  if (lane == 63) ws[w] = inc;
  __syncthreads();
  if (threadIdx.x == 0) { int r = 0; for (int k = 0; k < 8; ++k) { wb[k] = r; r += ws[k]; } }
  __syncthreads();
  int ex = blockbase[blockIdx.x] + wb[w] + inc - c;
  if (i < n) { rowptr[i] = ex; next[i] = ex; }
}

// ---- K3: scatter packed (src | etype<<17) records ----
__global__ __launch_bounds__(256) void k_scatter(
    const int* __restrict__ src, const int* __restrict__ dst, const int* __restrict__ et,
    int* __restrict__ next, unsigned* __restrict__ recs, int ne)
{
  int e = blockIdx.x * 256 + threadIdx.x;
  if (e >= ne) return;
  int d = dst[e];
  int pos = atomicAdd(&next[d], 1);
  recs[pos] = (unsigned)src[e] | ((unsigned)et[e] << 17);
}

// ---- K4: wave per dst, 2 edges in flight (lane halves), bf16 feat gather ----
__global__ __launch_bounds__(256) void k_agg(
    const int* __restrict__ rowptr, const unsigned* __restrict__ recs,
    const float* __restrict__ el, const float* __restrict__ er, const float* __restrict__ eeg,
    const unsigned* __restrict__ featp, float* __restrict__ out, int n)
{
  __shared__ float s_ee[32];
  if (threadIdx.x < 32) s_ee[threadIdx.x] = eeg[threadIdx.x];
  __syncthreads();
  int d = (blockIdx.x * 256 + threadIdx.x) >> 6;
  if (d >= n) return;
  int lane = threadIdx.x & 63;
  int half = lane >> 5;       // which edge of the pair
  int l    = lane & 31;       // dim-pair index: dims 2l, 2l+1
  int h    = l >> 3;          // head
  int beg = rowptr[d], end = rowptr[d + 1];
  float erd = er[d * NH + h];
  float accx = 0.f, accy = 0.f, den = 0.f;
  for (int i = beg + half; i < end; i += 2) {
    unsigned r = recs[i];
    int s = r & 0x1FFFF;
    int t = r >> 17;
    float sv = el[s * NH + h] + erd + s_ee[t * NH + h];
    sv = sv > 0.f ? sv : NEG_SLOPE * sv;
    float p = __expf(sv);
    den += p;
    unsigned u = featp[s * 32 + l];                 // 2 packed bf16 dims
    accx = fmaf(p, __uint_as_float(u << 16), accx);
    accy = fmaf(p, __uint_as_float(u & 0xFFFF0000u), accy);
  }
  den  += __shfl_xor(den, 32);
  accx += __shfl_xor(accx, 32);
  accy += __shfl_xor(accy, 32);
  if (half == 0) {
    float inv = den > 0.f ? 1.f / den : 0.f;
    ((float2*)out)[(size_t)d * 32 + l] = make_float2(accx * inv, accy * inv);
  }
}

extern "C" void kernel_launch(void* const* d_in, const int* in_sizes, int n_in,
                              void* d_out, int out_size, void* d_ws, size_t ws_size,
                              hipStream_t stream)
{
  const float* x        = (const float*)d_in[0];
  const int*   src      = (const int*)d_in[1];
  const int*   dst      = (const int*)d_in[2];
  const int*   etype    = (const int*)d_in[3];
  const float* fcW      = (const float*)d_in[4];
  const float* fceW     = (const float*)d_in[5];
  const float* edge_emb = (const float*)d_in[6];
  const float* attn_e   = (const float*)d_in[9];
  const float* attn_l   = (const float*)d_in[7];
  const float* attn_r   = (const float*)d_in[8];
  float* out = (float*)d_out;

  const int n  = in_sizes[0] / IN_DIM;   // 100000
  const int ne = in_sizes[1];            // 1600000
  const int nb = (n + 511) / 512;        // 196 scan blocks (<=256)

  char* ws = (char*)d_ws;
  size_t off = 0;
  unsigned short* featb = (unsigned short*)(ws + off); off += (size_t)n * HD * sizeof(unsigned short);
  float* el    = (float*)(ws + off); off += (size_t)n * NH * sizeof(float);
  float* er    = (float*)(ws + off); off += (size_t)n * NH * sizeof(float);
  float* ee    = (float*)(ws + off); off += 256;
  int* rowptr  = (int*)(ws + off);   off += ((size_t)n + 1) * sizeof(int);
  int* next    = (int*)(ws + off);   off += (size_t)n * sizeof(int);
  int* blocksum= (int*)(ws + off);   off += (size_t)nb * sizeof(int);
  int* blockbase=(int*)(ws + off);   off += (size_t)nb * sizeof(int);
  unsigned* recs = (unsigned*)(ws + off); off += (size_t)ne * sizeof(unsigned);

  hipMemsetAsync(rowptr, 0, (size_t)n * sizeof(int), stream);

  k1_feat<<<1024, 256, 0, stream>>>(x, fcW, attn_l, attn_r, featb, el, er, dst, rowptr, n, ne);
  k_psum<<<nb, 512, 0, stream>>>(rowptr, blocksum, n);
  k_scan_blk<<<1, 256, 0, stream>>>(blocksum, blockbase, nb, rowptr, n, ne,
                                    edge_emb, fceW, attn_e, ee);
  k_scan_apply<<<nb, 512, 0, stream>>>(rowptr, blockbase, next, n);
  k_scatter<<<(ne + 255) / 256, 256, 0, stream>>>(src, dst, etype, next, recs, ne);
  k_agg<<<((size_t)n * 64 + 255) / 256, 256, 0, stream>>>(rowptr, recs, el, er, ee,
                                                          (const unsigned*)featb, out, n);
}

// Round 5
// 276.119 us; speedup vs baseline: 2.7719x; 1.2684x over previous
//
#include <hip/hip_runtime.h>

#define NH 4
#define ND 16
#define HD 64
#define IN_DIM 128
#define NEG_SLOPE 0.2f

__device__ inline unsigned short f2bf(float f) {   // RNE fp32 -> bf16
  unsigned u = __float_as_uint(f);
  u += 0x7FFFu + ((u >> 16) & 1u);
  return (unsigned short)(u >> 16);
}

// ---- K1: feat(bf16) = x @ fc_W, el/er per node, fused dst-histogram tail ----
__global__ __launch_bounds__(256) void k1_feat(
    const float* __restrict__ x, const float* __restrict__ fcW,
    const float* __restrict__ attn_l, const float* __restrict__ attn_r,
    unsigned short* __restrict__ featb, float* __restrict__ el, float* __restrict__ er,
    const int* __restrict__ dst, int* __restrict__ cnt, int n, int ne)
{
  __shared__ float sW[IN_DIM * HD];   // 32 KB
  __shared__ float sx[16][IN_DIM];    // 8 KB
  for (int i = threadIdx.x; i < IN_DIM * HD; i += 256) sW[i] = fcW[i];
  const int grp = threadIdx.x >> 6;   // 0..3
  const int j   = threadIdx.x & 63;   // output column (h*16+d)
  const float al = attn_l[j], ar = attn_r[j];

  for (int base = blockIdx.x * 16; base < n; base += gridDim.x * 16) {
    __syncthreads();
    for (int i = threadIdx.x; i < 16 * IN_DIM; i += 256) {
      int r = i >> 7, c = i & 127;
      int row = base + r;
      sx[r][c] = (row < n) ? x[(size_t)row * IN_DIM + c] : 0.f;
    }
    __syncthreads();
    float a0 = 0.f, a1 = 0.f, a2 = 0.f, a3 = 0.f;
#pragma unroll 8
    for (int k = 0; k < IN_DIM; ++k) {
      float w = sW[k * HD + j];
      a0 = fmaf(sx[grp][k],      w, a0);
      a1 = fmaf(sx[grp + 4][k],  w, a1);
      a2 = fmaf(sx[grp + 8][k],  w, a2);
      a3 = fmaf(sx[grp + 12][k], w, a3);
    }
    float l0 = a0 * al, r0 = a0 * ar, l1 = a1 * al, r1 = a1 * ar;
    float l2 = a2 * al, r2 = a2 * ar, l3 = a3 * al, r3 = a3 * ar;
#pragma unroll
    for (int off = 8; off >= 1; off >>= 1) {
      l0 += __shfl_xor(l0, off); r0 += __shfl_xor(r0, off);
      l1 += __shfl_xor(l1, off); r1 += __shfl_xor(r1, off);
      l2 += __shfl_xor(l2, off); r2 += __shfl_xor(r2, off);
      l3 += __shfl_xor(l3, off); r3 += __shfl_xor(r3, off);
    }
    int h = j >> 4;
    int row;
    row = base + grp;
    if (row < n) { featb[(size_t)row * HD + j] = f2bf(a0);
      if ((j & 15) == 0) { el[row * NH + h] = l0; er[row * NH + h] = r0; } }
    row = base + grp + 4;
    if (row < n) { featb[(size_t)row * HD + j] = f2bf(a1);
      if ((j & 15) == 0) { el[row * NH + h] = l1; er[row * NH + h] = r1; } }
    row = base + grp + 8;
    if (row < n) { featb[(size_t)row * HD + j] = f2bf(a2);
      if ((j & 15) == 0) { el[row * NH + h] = l2; er[row * NH + h] = r2; } }
    row = base + grp + 12;
    if (row < n) { featb[(size_t)row * HD + j] = f2bf(a3);
      if ((j & 15) == 0) { el[row * NH + h] = l3; er[row * NH + h] = r3; } }
  }
  // fused dst histogram (cnt pre-zeroed by memset)
  for (int e = blockIdx.x * 256 + threadIdx.x; e < ne; e += gridDim.x * 256)
    atomicAdd(&cnt[dst[e]], 1);
}

// ---- K2a: per-block partial sums of counts (512 items / block) ----
__global__ __launch_bounds__(512) void k_psum(
    const int* __restrict__ cnt, int* __restrict__ blocksum, int n)
{
  __shared__ int ws[8];
  int i = blockIdx.x * 512 + threadIdx.x;
  int c = (i < n) ? cnt[i] : 0;
#pragma unroll
  for (int off = 32; off >= 1; off >>= 1) c += __shfl_xor(c, off);
  int lane = threadIdx.x & 63, w = threadIdx.x >> 6;
  if (lane == 0) ws[w] = c;
  __syncthreads();
  if (threadIdx.x == 0) {
    int r = 0;
#pragma unroll
    for (int k = 0; k < 8; ++k) r += ws[k];
    blocksum[blockIdx.x] = r;
  }
}

// ---- K2b: scan block sums (nb <= 256) + tiny ee[t][h] computation fused ----
__global__ __launch_bounds__(256) void k_scan_blk(
    const int* __restrict__ blocksum, int* __restrict__ blockbase,
    int nb, int* __restrict__ rowptr, int n, int ne,
    const float* __restrict__ edge_emb, const float* __restrict__ fc_e_W,
    const float* __restrict__ attn_e, float* __restrict__ ee)
{
  __shared__ int ws[4], wb[4];
  __shared__ float sef[8][128];
  int t = threadIdx.x;
  int c = (t < nb) ? blocksum[t] : 0;
  int lane = t & 63, w = t >> 6;
  int inc = c;
#pragma unroll
  for (int off = 1; off < 64; off <<= 1) {
    int v = __shfl_up(inc, off);
    if (lane >= off) inc += v;
  }
  if (lane == 63) ws[w] = inc;
  if (t < 128) {
    for (int r = 0; r < 8; ++r) {
      float acc = 0.f;
#pragma unroll
      for (int k = 0; k < 32; ++k) acc = fmaf(edge_emb[r * 32 + k], fc_e_W[k * 128 + t], acc);
      sef[r][t] = acc;
    }
  }
  __syncthreads();
  if (t == 0) { int r = 0; for (int k = 0; k < 4; ++k) { wb[k] = r; r += ws[k]; } }
  if (t < 32) {
    int r = t >> 2, h = t & 3;
    float acc = 0.f;
#pragma unroll
    for (int e2 = 0; e2 < 32; ++e2) acc += sef[r][h * 32 + e2] * attn_e[h * 32 + e2];
    ee[r * NH + h] = acc;
  }
  __syncthreads();
  if (t < nb) blockbase[t] = wb[w] + inc - c;
  if (t == 0) rowptr[n] = ne;
}

// ---- K2c: block-local scan + base; rowptr (in)=counts, (out)=offsets ----
__global__ __launch_bounds__(512) void k_scan_apply(
    int* __restrict__ rowptr, const int* __restrict__ blockbase,
    int* __restrict__ next, int n)
{
  __shared__ int ws[8], wb[8];
  int i = blockIdx.x * 512 + threadIdx.x;
  int c = (i < n) ? rowptr[i] : 0;
  int lane = threadIdx.x & 63, w = threadIdx.x >> 6;
  int inc = c;
#pragma unroll
  for (int off = 1; off < 64; off <<= 1) {
    int v = __shfl_up(inc, off);
    if (lane >= off) inc += v;
  }
  if (lane == 63) ws[w] = inc;
  __syncthreads();
  if (threadIdx.x == 0) { int r = 0; for (int k = 0; k < 8; ++k) { wb[k] = r; r += ws[k]; } }
  __syncthreads();
  int ex = blockbase[blockIdx.x] + wb[w] + inc - c;
  if (i < n) { rowptr[i] = ex; next[i] = ex; }
}

// ---- K3: dst-range-partitioned scatter (range r = blockIdx & 7 -> one XCD) ----
// Writers of any recs line share an XCD -> line stays in that L2, written back once.
__global__ __launch_bounds__(256) void k_scatter_r(
    const int* __restrict__ src, const int* __restrict__ dst, const int* __restrict__ et,
    int* __restrict__ next, unsigned* __restrict__ recs, int ne, int n)
{
  const int r = blockIdx.x & 7;
  const int g = blockIdx.x >> 3;
  const int G = gridDim.x >> 3;
  const int chunk = (n + 7) >> 3;
  const int lo = r * chunk;
  const int hi = (lo + chunk < n) ? lo + chunk : n;
  for (int e = g * 256 + threadIdx.x; e < ne; e += G * 256) {
    int d = dst[e];
    if (d >= lo && d < hi) {
      int pos = atomicAdd(&next[d], 1);
      recs[pos] = (unsigned)src[e] | ((unsigned)et[e] << 17);
    }
  }
}

// ---- K4: wave per dst, 4 edges in flight (16-lane groups), bf16 feat gather ----
__global__ __launch_bounds__(256) void k_agg(
    const int* __restrict__ rowptr, const unsigned* __restrict__ recs,
    const float* __restrict__ el, const float* __restrict__ er, const float* __restrict__ eeg,
    const uint2* __restrict__ featp, float* __restrict__ out, int n)
{
  __shared__ float s_ee[32];
  if (threadIdx.x < 32) s_ee[threadIdx.x] = eeg[threadIdx.x];
  __syncthreads();
  int d = (blockIdx.x * 256 + threadIdx.x) >> 6;
  if (d >= n) return;
  int lane = threadIdx.x & 63;
  int q = lane >> 4;          // which edge of the quad
  int l = lane & 15;          // dim quad: dims 4l..4l+3
  int h = l >> 2;             // head
  int beg = rowptr[d], end = rowptr[d + 1];
  float erd = er[d * NH + h];
  float a0 = 0.f, a1 = 0.f, a2 = 0.f, a3 = 0.f, den = 0.f;
  for (int i = beg + q; i < end; i += 4) {
    unsigned rr = recs[i];
    int s = rr & 0x1FFFF;
    int t = rr >> 17;
    float sv = el[s * NH + h] + erd + s_ee[t * NH + h];
    sv = sv > 0.f ? sv : NEG_SLOPE * sv;
    float p = __expf(sv);
    den += p;
    uint2 u = featp[s * 16 + l];               // 4 packed bf16 dims
    a0 = fmaf(p, __uint_as_float(u.x << 16), a0);
    a1 = fmaf(p, __uint_as_float(u.x & 0xFFFF0000u), a1);
    a2 = fmaf(p, __uint_as_float(u.y << 16), a2);
    a3 = fmaf(p, __uint_as_float(u.y & 0xFFFF0000u), a3);
  }
#pragma unroll
  for (int off = 16; off <= 32; off <<= 1) {
    den += __shfl_xor(den, off);
    a0 += __shfl_xor(a0, off);
    a1 += __shfl_xor(a1, off);
    a2 += __shfl_xor(a2, off);
    a3 += __shfl_xor(a3, off);
  }
  if (q == 0) {
    float inv = den > 0.f ? 1.f / den : 0.f;
    ((float4*)out)[(size_t)d * 16 + l] = make_float4(a0 * inv, a1 * inv, a2 * inv, a3 * inv);
  }
}

extern "C" void kernel_launch(void* const* d_in, const int* in_sizes, int n_in,
                              void* d_out, int out_size, void* d_ws, size_t ws_size,
                              hipStream_t stream)
{
  const float* x        = (const float*)d_in[0];
  const int*   src      = (const int*)d_in[1];
  const int*   dst      = (const int*)d_in[2];
  const int*   etype    = (const int*)d_in[3];
  const float* fcW      = (const float*)d_in[4];
  const float* fceW     = (const float*)d_in[5];
  const float* edge_emb = (const float*)d_in[6];
  const float* attn_l   = (const float*)d_in[7];
  const float* attn_r   = (const float*)d_in[8];
  const float* attn_e   = (const float*)d_in[9];
  float* out = (float*)d_out;

  const int n  = in_sizes[0] / IN_DIM;   // 100000
  const int ne = in_sizes[1];            // 1600000
  const int nb = (n + 511) / 512;        // 196 scan blocks (<=256)

  char* ws = (char*)d_ws;
  size_t off = 0;
  unsigned short* featb = (unsigned short*)(ws + off); off += (size_t)n * HD * sizeof(unsigned short);
  float* el    = (float*)(ws + off); off += (size_t)n * NH * sizeof(float);
  float* er    = (float*)(ws + off); off += (size_t)n * NH * sizeof(float);
  float* ee    = (float*)(ws + off); off += 256;
  int* rowptr  = (int*)(ws + off);   off += ((size_t)n + 1) * sizeof(int);
  int* next    = (int*)(ws + off);   off += (size_t)n * sizeof(int);
  int* blocksum= (int*)(ws + off);   off += (size_t)nb * sizeof(int);
  int* blockbase=(int*)(ws + off);   off += (size_t)nb * sizeof(int);
  unsigned* recs = (unsigned*)(ws + off); off += (size_t)ne * sizeof(unsigned);

  hipMemsetAsync(rowptr, 0, (size_t)n * sizeof(int), stream);

  k1_feat<<<1024, 256, 0, stream>>>(x, fcW, attn_l, attn_r, featb, el, er, dst, rowptr, n, ne);
  k_psum<<<nb, 512, 0, stream>>>(rowptr, blocksum, n);
  k_scan_blk<<<1, 256, 0, stream>>>(blocksum, blockbase, nb, rowptr, n, ne,
                                    edge_emb, fceW, attn_e, ee);
  k_scan_apply<<<nb, 512, 0, stream>>>(rowptr, blockbase, next, n);
  k_scatter_r<<<1024, 256, 0, stream>>>(src, dst, etype, next, recs, ne, n);
  k_agg<<<((size_t)n * 64 + 255) / 256, 256, 0, stream>>>(rowptr, recs, el, er, ee,
                                                          (const uint2*)featb, out, n);
}

// Round 6
// 257.859 us; speedup vs baseline: 2.9682x; 1.0708x over previous
//
#include <hip/hip_runtime.h>

#define NH 4
#define ND 16
#define HD 64
#define IN_DIM 128
#define NEG_SLOPE 0.2f

typedef short bf8 __attribute__((ext_vector_type(8)));   // 8 bf16 in 4 VGPRs
typedef float f4  __attribute__((ext_vector_type(4)));

__device__ inline unsigned short f2bf(float f) {   // RNE fp32 -> bf16
  unsigned u = __float_as_uint(f);
  u += 0x7FFFu + ((u >> 16) & 1u);
  return (unsigned short)(u >> 16);
}

// ---- K1: feat(bf16) = x @ fc_W via MFMA, + el/er per node ----
// Block = 4 waves, 64 rows (wave w -> rows base+16w..+15). W^T staged in LDS.
__global__ __launch_bounds__(256) void k1_mfma(
    const float* __restrict__ x, const float* __restrict__ fcW,
    const float* __restrict__ attn_l, const float* __restrict__ attn_r,
    unsigned short* __restrict__ featb, float4* __restrict__ el4, float4* __restrict__ er4,
    int n)
{
  __shared__ unsigned short wt[HD][IN_DIM + 8];   // W^T bf16, padded (17.4 KB)
  for (int idx = threadIdx.x; idx < IN_DIM * HD; idx += 256) {
    int k = idx >> 6, j = idx & 63;
    wt[j][k] = f2bf(fcW[idx]);
  }
  __syncthreads();

  const int w  = threadIdx.x >> 6;    // wave 0..3
  const int l  = threadIdx.x & 63;
  const int lr = l & 15;
  const int lg = l >> 4;
  const int rowbase = blockIdx.x * 64 + w * 16;

  // A source row (mapping: A row = lane&15, k = (lane>>4)*8 + i)
  int arow = rowbase + lr;
  if (arow >= n) arow = n - 1;                     // clamp; stores predicated
  const float* xp = x + (size_t)arow * IN_DIM + lg * 8;

  f4 acc[4] = {};                                  // one per n-tile (= head)
#pragma unroll
  for (int kc = 0; kc < 4; ++kc) {
    float4 a0 = *(const float4*)(xp + kc * 32);
    float4 a1 = *(const float4*)(xp + kc * 32 + 4);
    bf8 af;
    af[0] = (short)f2bf(a0.x); af[1] = (short)f2bf(a0.y);
    af[2] = (short)f2bf(a0.z); af[3] = (short)f2bf(a0.w);
    af[4] = (short)f2bf(a1.x); af[5] = (short)f2bf(a1.y);
    af[6] = (short)f2bf(a1.z); af[7] = (short)f2bf(a1.w);
#pragma unroll
    for (int nt = 0; nt < 4; ++nt) {
      bf8 bfr = *(const bf8*)&wt[nt * 16 + lr][kc * 32 + lg * 8];
      acc[nt] = __builtin_amdgcn_mfma_f32_16x16x32_bf16(af, bfr, acc[nt], 0, 0, 0);
    }
  }

  // D mapping: row = rowbase + lg*4 + r, col = nt*16 + lr  (head h == nt)
  float al[NH], ar[NH];
#pragma unroll
  for (int h = 0; h < NH; ++h) { al[h] = attn_l[h * 16 + lr]; ar[h] = attn_r[h * 16 + lr]; }

#pragma unroll
  for (int r = 0; r < 4; ++r) {
    int grow = rowbase + lg * 4 + r;
    bool ok = grow < n;
    if (ok) {
#pragma unroll
      for (int nt = 0; nt < 4; ++nt)
        featb[(size_t)grow * HD + nt * 16 + lr] = f2bf(acc[nt][r]);
    }
    float pl[NH], pr[NH];
#pragma unroll
    for (int h = 0; h < NH; ++h) { pl[h] = acc[h][r] * al[h]; pr[h] = acc[h][r] * ar[h]; }
#pragma unroll
    for (int off = 1; off < 16; off <<= 1) {
#pragma unroll
      for (int h = 0; h < NH; ++h) {
        pl[h] += __shfl_xor(pl[h], off);
        pr[h] += __shfl_xor(pr[h], off);
      }
    }
    if (ok && lr == 0) {
      el4[grow] = make_float4(pl[0], pl[1], pl[2], pl[3]);
      er4[grow] = make_float4(pr[0], pr[1], pr[2], pr[3]);
    }
  }
}

// ---- K1b: dst histogram, range-partitioned (range = blockIdx & 7 -> one XCD) ----
__global__ __launch_bounds__(256) void k_hist_r(
    const int* __restrict__ dst, int* __restrict__ cnt, int ne, int n)
{
  const int r = blockIdx.x & 7;
  const int g = blockIdx.x >> 3;
  const int G = gridDim.x >> 3;
  const int chunk = (n + 7) >> 3;
  const int lo = r * chunk;
  const int hi = (lo + chunk < n) ? lo + chunk : n;
  for (int e = g * 256 + threadIdx.x; e < ne; e += G * 256) {
    int d = dst[e];
    if (d >= lo && d < hi) atomicAdd(&cnt[d], 1);
  }
}

// ---- K2a: per-block partial sums of counts (512 items / block) ----
__global__ __launch_bounds__(512) void k_psum(
    const int* __restrict__ cnt, int* __restrict__ blocksum, int n)
{
  __shared__ int ws[8];
  int i = blockIdx.x * 512 + threadIdx.x;
  int c = (i < n) ? cnt[i] : 0;
#pragma unroll
  for (int off = 32; off >= 1; off >>= 1) c += __shfl_xor(c, off);
  int lane = threadIdx.x & 63, w = threadIdx.x >> 6;
  if (lane == 0) ws[w] = c;
  __syncthreads();
  if (threadIdx.x == 0) {
    int r = 0;
#pragma unroll
    for (int k = 0; k < 8; ++k) r += ws[k];
    blocksum[blockIdx.x] = r;
  }
}

// ---- K2b: scan block sums (nb <= 256) + tiny ee[t][h] computation fused ----
__global__ __launch_bounds__(256) void k_scan_blk(
    const int* __restrict__ blocksum, int* __restrict__ blockbase,
    int nb, int* __restrict__ rowptr, int n, int ne,
    const float* __restrict__ edge_emb, const float* __restrict__ fc_e_W,
    const float* __restrict__ attn_e, float* __restrict__ ee)
{
  __shared__ int ws[4], wb[4];
  __shared__ float sef[8][128];
  int t = threadIdx.x;
  int c = (t < nb) ? blocksum[t] : 0;
  int lane = t & 63, w = t >> 6;
  int inc = c;
#pragma unroll
  for (int off = 1; off < 64; off <<= 1) {
    int v = __shfl_up(inc, off);
    if (lane >= off) inc += v;
  }
  if (lane == 63) ws[w] = inc;
  if (t < 128) {
    for (int r = 0; r < 8; ++r) {
      float acc = 0.f;
#pragma unroll
      for (int k = 0; k < 32; ++k) acc = fmaf(edge_emb[r * 32 + k], fc_e_W[k * 128 + t], acc);
      sef[r][t] = acc;
    }
  }
  __syncthreads();
  if (t == 0) { int r = 0; for (int k = 0; k < 4; ++k) { wb[k] = r; r += ws[k]; } }
  if (t < 32) {
    int r = t >> 2, h = t & 3;
    float acc = 0.f;
#pragma unroll
    for (int e2 = 0; e2 < 32; ++e2) acc += sef[r][h * 32 + e2] * attn_e[h * 32 + e2];
    ee[r * NH + h] = acc;
  }
  __syncthreads();
  if (t < nb) blockbase[t] = wb[w] + inc - c;
  if (t == 0) rowptr[n] = ne;
}

// ---- K2c: block-local scan + base; rowptr (in)=counts, (out)=offsets ----
__global__ __launch_bounds__(512) void k_scan_apply(
    int* __restrict__ rowptr, const int* __restrict__ blockbase,
    int* __restrict__ next, int n)
{
  __shared__ int ws[8], wb[8];
  int i = blockIdx.x * 512 + threadIdx.x;
  int c = (i < n) ? rowptr[i] : 0;
  int lane = threadIdx.x & 63, w = threadIdx.x >> 6;
  int inc = c;
#pragma unroll
  for (int off = 1; off < 64; off <<= 1) {
    int v = __shfl_up(inc, off);
    if (lane >= off) inc += v;
  }
  if (lane == 63) ws[w] = inc;
  __syncthreads();
  if (threadIdx.x == 0) { int r = 0; for (int k = 0; k < 8; ++k) { wb[k] = r; r += ws[k]; } }
  __syncthreads();
  int ex = blockbase[blockIdx.x] + wb[w] + inc - c;
  if (i < n) { rowptr[i] = ex; next[i] = ex; }
}

// ---- K3: dst-range-partitioned scatter (range r = blockIdx & 7 -> one XCD) ----
__global__ __launch_bounds__(256) void k_scatter_r(
    const int* __restrict__ src, const int* __restrict__ dst, const int* __restrict__ et,
    int* __restrict__ next, unsigned* __restrict__ recs, int ne, int n)
{
  const int r = blockIdx.x & 7;
  const int g = blockIdx.x >> 3;
  const int G = gridDim.x >> 3;
  const int chunk = (n + 7) >> 3;
  const int lo = r * chunk;
  const int hi = (lo + chunk < n) ? lo + chunk : n;
  for (int e = g * 256 + threadIdx.x; e < ne; e += G * 256) {
    int d = dst[e];
    if (d >= lo && d < hi) {
      int pos = atomicAdd(&next[d], 1);
      recs[pos] = (unsigned)src[e] | ((unsigned)et[e] << 17);
    }
  }
}

// ---- K4: wave per dst, 4 edges in flight (16-lane groups), bf16 feat gather ----
__global__ __launch_bounds__(256) void k_agg(
    const int* __restrict__ rowptr, const unsigned* __restrict__ recs,
    const float* __restrict__ el, const float* __restrict__ er, const float* __restrict__ eeg,
    const uint2* __restrict__ featp, float* __restrict__ out, int n)
{
  __shared__ float s_ee[32];
  if (threadIdx.x < 32) s_ee[threadIdx.x] = eeg[threadIdx.x];
  __syncthreads();
  int d = (blockIdx.x * 256 + threadIdx.x) >> 6;
  if (d >= n) return;
  int lane = threadIdx.x & 63;
  int q = lane >> 4;          // which edge of the quad
  int l = lane & 15;          // dim quad: dims 4l..4l+3
  int h = l >> 2;             // head
  int beg = rowptr[d], end = rowptr[d + 1];
  float erd = er[d * NH + h];
  float a0 = 0.f, a1 = 0.f, a2 = 0.f, a3 = 0.f, den = 0.f;
  for (int i = beg + q; i < end; i += 4) {
    unsigned rr = recs[i];
    int s = rr & 0x1FFFF;
    int t = rr >> 17;
    float sv = el[s * NH + h] + erd + s_ee[t * NH + h];
    sv = sv > 0.f ? sv : NEG_SLOPE * sv;
    float p = __expf(sv);
    den += p;
    uint2 u = featp[s * 16 + l];               // 4 packed bf16 dims
    a0 = fmaf(p, __uint_as_float(u.x << 16), a0);
    a1 = fmaf(p, __uint_as_float(u.x & 0xFFFF0000u), a1);
    a2 = fmaf(p, __uint_as_float(u.y << 16), a2);
    a3 = fmaf(p, __uint_as_float(u.y & 0xFFFF0000u), a3);
  }
#pragma unroll
  for (int off = 16; off <= 32; off <<= 1) {
    den += __shfl_xor(den, off);
    a0 += __shfl_xor(a0, off);
    a1 += __shfl_xor(a1, off);
    a2 += __shfl_xor(a2, off);
    a3 += __shfl_xor(a3, off);
  }
  if (q == 0) {
    float inv = den > 0.f ? 1.f / den : 0.f;
    ((float4*)out)[(size_t)d * 16 + l] = make_float4(a0 * inv, a1 * inv, a2 * inv, a3 * inv);
  }
}

extern "C" void kernel_launch(void* const* d_in, const int* in_sizes, int n_in,
                              void* d_out, int out_size, void* d_ws, size_t ws_size,
                              hipStream_t stream)
{
  const float* x        = (const float*)d_in[0];
  const int*   src      = (const int*)d_in[1];
  const int*   dst      = (const int*)d_in[2];
  const int*   etype    = (const int*)d_in[3];
  const float* fcW      = (const float*)d_in[4];
  const float* fceW     = (const float*)d_in[5];
  const float* edge_emb = (const float*)d_in[6];
  const float* attn_l   = (const float*)d_in[7];
  const float* attn_r   = (const float*)d_in[8];
  const float* attn_e   = (const float*)d_in[9];
  float* out = (float*)d_out;

  const int n  = in_sizes[0] / IN_DIM;   // 100000
  const int ne = in_sizes[1];            // 1600000
  const int nb = (n + 511) / 512;        // 196 scan blocks (<=256)

  char* ws = (char*)d_ws;
  size_t off = 0;
  unsigned short* featb = (unsigned short*)(ws + off); off += (size_t)n * HD * sizeof(unsigned short);
  float* el    = (float*)(ws + off); off += (size_t)n * NH * sizeof(float);
  float* er    = (float*)(ws + off); off += (size_t)n * NH * sizeof(float);
  float* ee    = (float*)(ws + off); off += 256;
  int* rowptr  = (int*)(ws + off);   off += ((size_t)n + 1) * sizeof(int);
  int* next    = (int*)(ws + off);   off += (size_t)n * sizeof(int);
  int* blocksum= (int*)(ws + off);   off += (size_t)nb * sizeof(int);
  int* blockbase=(int*)(ws + off);   off += (size_t)nb * sizeof(int);
  unsigned* recs = (unsigned*)(ws + off); off += (size_t)ne * sizeof(unsigned);

  hipMemsetAsync(rowptr, 0, (size_t)n * sizeof(int), stream);

  k1_mfma<<<(n + 63) / 64, 256, 0, stream>>>(x, fcW, attn_l, attn_r, featb,
                                             (float4*)el, (float4*)er, n);
  k_hist_r<<<1024, 256, 0, stream>>>(dst, rowptr, ne, n);
  k_psum<<<nb, 512, 0, stream>>>(rowptr, blocksum, n);
  k_scan_blk<<<1, 256, 0, stream>>>(blocksum, blockbase, nb, rowptr, n, ne,
                                    edge_emb, fceW, attn_e, ee);
  k_scan_apply<<<nb, 512, 0, stream>>>(rowptr, blockbase, next, n);
  k_scatter_r<<<1024, 256, 0, stream>>>(src, dst, etype, next, recs, ne, n);
  k_agg<<<((size_t)n * 64 + 255) / 256, 256, 0, stream>>>(rowptr, recs, el, er, ee,
                                                          (const uint2*)featb, out, n);
}